// Round 7
// baseline (386.001 us; speedup 1.0000x reference)
//
#include <hip/hip_runtime.h>

// Problem constants
#define BB 2
#define SS 2048
#define DD 1024
#define HH 16
#define HD 64
#define CS 512
#define NC 4
#define TD 3072            // 3*D
#define MM 4096            // B*S tokens

typedef __attribute__((ext_vector_type(8))) short short8;
typedef __attribute__((ext_vector_type(4))) float floatx4;

__device__ __forceinline__ float bf2f(unsigned short h) {
  union { unsigned int u; float f; } v; v.u = ((unsigned int)h) << 16; return v.f;
}
__device__ __forceinline__ unsigned short f2bf(float f) {
  union { float f; unsigned int u; } v; v.f = f;
  unsigned int r = (v.u + 0x7fffu + ((v.u >> 16) & 1u)) >> 16;
  return (unsigned short)r;
}
__device__ __forceinline__ short8 ld8f(const float* p) {
  floatx4 f0 = *(const floatx4*)p;
  floatx4 f1 = *(const floatx4*)(p + 4);
  short8 o;
  o[0] = (short)f2bf(f0[0]); o[1] = (short)f2bf(f0[1]);
  o[2] = (short)f2bf(f0[2]); o[3] = (short)f2bf(f0[3]);
  o[4] = (short)f2bf(f1[0]); o[5] = (short)f2bf(f1[1]);
  o[6] = (short)f2bf(f1[2]); o[7] = (short)f2bf(f1[3]);
  return o;
}
// exact bf16 *= 0.125 (exponent shift; RNE of exact value)
__device__ __forceinline__ short8 scale8_eighth(short8 a) {
  short8 o;
#pragma unroll
  for (int j = 0; j < 8; ++j) o[j] = (short)f2bf(bf2f((unsigned short)a[j]) * 0.125f);
  return o;
}
__device__ __forceinline__ void async16(const void* g, void* l) {
  __builtin_amdgcn_global_load_lds((const __attribute__((address_space(1))) void*)g,
                                   (__attribute__((address_space(3))) void*)l, 16, 0, 0);
}

// ---------------------------------------------------------------------------
// f32 -> bf16 convert (8 elems/thread)
// ---------------------------------------------------------------------------
__global__ __launch_bounds__(256) void cvt_bf16(const float* __restrict__ in,
                                                unsigned short* __restrict__ out, int n) {
  int i = (blockIdx.x * 256 + threadIdx.x) * 8;
  if (i < n) *(short8*)(out + i) = ld8f(in + i);
}

// ---------------------------------------------------------------------------
// GEMM: C[M,N] = A[M,K] * W[N,K]^T + bias[N]. A bf16 (global_load_lds);
// W bf16 (global_load_lds) or f32 (ld8f + ds_write). C f32 or bf16.
// 128x128 tile, BK=32, 256 threads (4 waves 2x2), m97-style staging.
// ---------------------------------------------------------------------------
template <int W_F32, int C_F32>
__global__ __launch_bounds__(256) void gemm_bt_bias(
    const unsigned short* __restrict__ A, const void* __restrict__ Wv,
    const float* __restrict__ bias, void* __restrict__ Cv, int M, int N, int K) {
  __shared__ unsigned short sA[128 * 32];
  __shared__ unsigned short sB[128 * 32];
  const int tid = threadIdx.x;
  const int wid = tid >> 6, lane = tid & 63;
  const int quad = lane >> 4, l15 = lane & 15;
  const int wm = wid & 1, wn = wid >> 1;
  const int bm = blockIdx.y, bn = blockIdx.x;

  floatx4 acc[4][4];
#pragma unroll
  for (int i = 0; i < 4; ++i)
#pragma unroll
    for (int j = 0; j < 4; ++j) acc[i][j] = (floatx4){0.f, 0.f, 0.f, 0.f};

  const int r = tid >> 2;            // 0..63
  const int kc = (tid & 3) * 8;      // 0,8,16,24
  const unsigned short* gA = A + (size_t)(bm * 128 + r) * K + kc;
  const float*          gWf = (const float*)Wv          + (size_t)(bn * 128 + r) * K + kc;
  const unsigned short* gWh = (const unsigned short*)Wv + (size_t)(bn * 128 + r) * K + kc;
  unsigned short* lA = sA + wid * 512;  // wave-uniform base; HW appends lane*16B
  unsigned short* lB = sB + wid * 512;

  for (int k0 = 0; k0 < K; k0 += 32) {
    async16(gA + k0, lA);
    async16(gA + (size_t)64 * K + k0, lA + 2048);
    if (W_F32) {
      short8 b0 = ld8f(gWf + k0);
      short8 b1 = ld8f(gWf + (size_t)64 * K + k0);
      *(short8*)(sB + r * 32 + kc) = b0;
      *(short8*)(sB + (64 + r) * 32 + kc) = b1;
    } else {
      async16(gWh + k0, lB);
      async16(gWh + (size_t)64 * K + k0, lB + 2048);
    }
    __syncthreads();

    short8 af[4], bfr[4];
#pragma unroll
    for (int i = 0; i < 4; ++i)
      af[i] = *(const short8*)(sA + (wm * 64 + i * 16 + l15) * 32 + quad * 8);
#pragma unroll
    for (int j = 0; j < 4; ++j)
      bfr[j] = *(const short8*)(sB + (wn * 64 + j * 16 + l15) * 32 + quad * 8);
#pragma unroll
    for (int i = 0; i < 4; ++i)
#pragma unroll
      for (int j = 0; j < 4; ++j)
        acc[i][j] = __builtin_amdgcn_mfma_f32_16x16x32_bf16(af[i], bfr[j], acc[i][j], 0, 0, 0);
    __syncthreads();
  }

  // Epilogue. C/D layout: col = lane&15, row = quad*4 + reg.
#pragma unroll
  for (int j = 0; j < 4; ++j) {
    int n = bn * 128 + wn * 64 + j * 16 + l15;
    float bv = bias[n];
#pragma unroll
    for (int i = 0; i < 4; ++i) {
      int mrow = bm * 128 + wm * 64 + i * 16 + quad * 4;
#pragma unroll
      for (int rr = 0; rr < 4; ++rr) {
        float v = acc[i][j][rr] + bv;
        if (C_F32) ((float*)Cv)[(size_t)(mrow + rr) * N + n] = v;
        else ((unsigned short*)Cv)[(size_t)(mrow + rr) * N + n] = f2bf(v);
      }
    }
  }
}

// ---------------------------------------------------------------------------
// Local attention: seq len nc=4 across chunks, one wave per (b,c,h).
// Reads packed QKV1 (bf16, stride TD) rows t1=b*2048+n*512+c; writes O1
// (bf16, stride DD) rows permuted t2=n*1024+b*512+c.
// ---------------------------------------------------------------------------
__global__ __launch_bounds__(256) void attn_local(const unsigned short* __restrict__ QKV,
                                                  unsigned short* __restrict__ O) {
  const int tid = threadIdx.x;
  const int wid = tid >> 6, lane = tid & 63;
  const int idx = blockIdx.x * 4 + wid;  // (b*512 + c)*16 + h
  const int h = idx & 15, c = (idx >> 4) & 511, b = idx >> 13;

  float q[NC], k[NC], v[NC];
#pragma unroll
  for (int n = 0; n < NC; ++n) {
    size_t base = (size_t)(b * SS + n * CS + c) * TD + h * HD + lane;
    q[n] = bf2f(QKV[base]);
    k[n] = bf2f(QKV[base + DD]);
    v[n] = bf2f(QKV[base + 2 * DD]);
  }
  float s[NC][NC];
#pragma unroll
  for (int m = 0; m < NC; ++m)
#pragma unroll
    for (int n = 0; n < NC; ++n) {
      float p = q[m] * k[n];
#pragma unroll
      for (int off = 32; off >= 1; off >>= 1) p += __shfl_xor(p, off);
      s[m][n] = p * 0.125f;
    }
#pragma unroll
  for (int m = 0; m < NC; ++m) {
    float mx = fmaxf(fmaxf(s[m][0], s[m][1]), fmaxf(s[m][2], s[m][3]));
    float e[NC], sum = 0.f;
#pragma unroll
    for (int n = 0; n < NC; ++n) { e[n] = __expf(s[m][n] - mx); sum += e[n]; }
    float o = (e[0] * v[0] + e[1] * v[1] + e[2] * v[2] + e[3] * v[3]) / sum;
    O[(size_t)(m * (BB * CS) + b * CS + c) * DD + h * HD + lane] = f2bf(o);
  }
}

// ---------------------------------------------------------------------------
// V pre-transpose: QKV2 V-columns -> VT[b][h][dim(64)][token(2048)].
// 64x64 tiles via swizzled LDS. Grid (bh=32, stile=32).
// ---------------------------------------------------------------------------
__global__ __launch_bounds__(256) void transpose_v(const unsigned short* __restrict__ QKV,
                                                   unsigned short* __restrict__ VT) {
  __shared__ unsigned short sT[64 * 64];
  const int tid = threadIdx.x;
  const int bh = blockIdx.x, b = bh >> 4, h = bh & 15;
  const int s0 = blockIdx.y * 64;
#pragma unroll
  for (int it = 0; it < 2; ++it) {
    int C = it * 256 + tid;
    int t = C >> 3, dc = C & 7;
    short8 v = *(const short8*)(QKV + (size_t)(b * SS + s0 + t) * TD + 2 * DD + h * HD + dc * 8);
    *(short8*)(sT + t * 64 + ((dc ^ (t & 7)) << 3)) = v;
  }
  __syncthreads();
#pragma unroll
  for (int it = 0; it < 2; ++it) {
    int C = it * 256 + tid;
    int d = C >> 3, tc = C & 7;
    short8 o;
#pragma unroll
    for (int j = 0; j < 8; ++j) {
      int t = tc * 8 + j;
      o[j] = (short)sT[t * 64 + (((d >> 3) ^ (t & 7)) << 3) + (d & 7)];
    }
    *(short8*)(VT + ((size_t)(bh * 64 + d)) * SS + s0 + tc * 8) = o;
  }
}

// ---------------------------------------------------------------------------
// Global attention, barrier-free: K-frags and VT-frags read directly from
// global (L1/L2-resident tiles); LDS holds only the wave-private P buffer.
// 32 q-rows/wave (2 row-groups), 128 q/block. Streaming exp-sum with
// truncation-rounded P and bias-cancelling lsum. Grid (x=bh, y=SS/128).
// ---------------------------------------------------------------------------
__global__ __launch_bounds__(256) void attn_global(
    const unsigned short* __restrict__ Q, const unsigned short* __restrict__ Kp,
    const unsigned short* __restrict__ VT, unsigned short* __restrict__ O) {
  __shared__ unsigned short sP[4][32 * 64];
  const int tid = threadIdx.x;
  const int wid = tid >> 6, lane = tid & 63;
  const int quad = lane >> 4, l15 = lane & 15;
  const int bh = blockIdx.x;
  const int b = bh >> 4, h = bh & 15;
  const int q0 = blockIdx.y * 128 + wid * 32;

  // Q A-frags for 2 row-groups, pre-scaled by 1/8 (exact)
  short8 qf[2][2];
#pragma unroll
  for (int g = 0; g < 2; ++g) {
    const unsigned short* qr = Q + (size_t)(b * SS + q0 + g * 16 + l15) * TD + h * HD + quad * 8;
    qf[g][0] = scale8_eighth(*(const short8*)qr);
    qf[g][1] = scale8_eighth(*(const short8*)(qr + 32));
  }

  float lsum[2][4];
  floatx4 oacc[2][4];
#pragma unroll
  for (int g = 0; g < 2; ++g)
#pragma unroll
    for (int s = 0; s < 4; ++s) { lsum[g][s] = 0.f; oacc[g][s] = (floatx4){0.f, 0.f, 0.f, 0.f}; }

  unsigned short* myP = &sP[wid][0];
  const unsigned short* vbase = VT + (size_t)(bh * 64) * SS;

  for (int kt = 0; kt < SS / 64; ++kt) {
    const int kbase = kt * 64;

    // S = (Q/8) K^T; K B-frags straight from global (lane n=key reads 16B)
    floatx4 sacc[2][4];
#pragma unroll
    for (int sub = 0; sub < 4; ++sub) {
      int key = sub * 16 + l15;
      const unsigned short* kr = Kp + (size_t)(b * SS + kbase + key) * TD + h * HD + quad * 8;
      short8 kf0 = *(const short8*)kr;
      short8 kf1 = *(const short8*)(kr + 32);
#pragma unroll
      for (int g = 0; g < 2; ++g) {
        floatx4 z = (floatx4){0.f, 0.f, 0.f, 0.f};
        z = __builtin_amdgcn_mfma_f32_16x16x32_bf16(qf[g][0], kf0, z, 0, 0, 0);
        z = __builtin_amdgcn_mfma_f32_16x16x32_bf16(qf[g][1], kf1, z, 0, 0, 0);
        sacc[g][sub] = z;
      }
    }

    // streaming exp; truncate to bf16 for P, accumulate the SAME truncated
    // value into lsum (systematic truncation bias cancels in the ratio)
#pragma unroll
    for (int g = 0; g < 2; ++g)
#pragma unroll
      for (int sub = 0; sub < 4; ++sub) {
        int kc8 = sub * 2 + (l15 >> 3), k7 = l15 & 7;
#pragma unroll
        for (int rr = 0; rr < 4; ++rr) {
          unsigned int u = __float_as_uint(__expf(sacc[g][sub][rr]));
          lsum[g][rr] += __uint_as_float(u & 0xffff0000u);
          int row = g * 16 + quad * 4 + rr;
          myP[row * 64 + (((kc8 ^ (row & 7) ^ ((row >> 3) << 1))) << 3) + k7] =
              (unsigned short)(u >> 16);
        }
      }
    __asm__ volatile("s_waitcnt lgkmcnt(0)" ::: "memory");  // wave-private RAW

    // P A-frags (row-group g, key-chunk c)
    short8 pf[2][2];
#pragma unroll
    for (int g = 0; g < 2; ++g) {
      int row = g * 16 + l15;
      int sw = (row & 7) ^ ((row >> 3) << 1);
#pragma unroll
      for (int c = 0; c < 2; ++c)
        pf[g][c] = *(const short8*)(myP + row * 64 + (((c * 4 + quad) ^ sw) << 3));
    }

    // O += P * V; VT B-frags straight from global (lane n=dim reads 16B)
#pragma unroll
    for (int sub = 0; sub < 4; ++sub) {
      int n = sub * 16 + l15;
      const unsigned short* vr = vbase + (size_t)n * SS + kbase + quad * 8;
      short8 vt0 = *(const short8*)vr;
      short8 vt1 = *(const short8*)(vr + 32);
#pragma unroll
      for (int g = 0; g < 2; ++g) {
        oacc[g][sub] = __builtin_amdgcn_mfma_f32_16x16x32_bf16(pf[g][0], vt0, oacc[g][sub], 0, 0, 0);
        oacc[g][sub] = __builtin_amdgcn_mfma_f32_16x16x32_bf16(pf[g][1], vt1, oacc[g][sub], 0, 0, 0);
      }
    }
  }

  // lsum reduce across the quad's 16 lanes, then normalize & store (RNE)
  float linv[2][4];
#pragma unroll
  for (int g = 0; g < 2; ++g)
#pragma unroll
    for (int rr = 0; rr < 4; ++rr) {
      float t = lsum[g][rr];
#pragma unroll
      for (int off = 8; off >= 1; off >>= 1) t += __shfl_xor(t, off);
      linv[g][rr] = 1.f / t;
    }
#pragma unroll
  for (int g = 0; g < 2; ++g)
#pragma unroll
    for (int sub = 0; sub < 4; ++sub)
#pragma unroll
      for (int rr = 0; rr < 4; ++rr) {
        int row = b * SS + q0 + g * 16 + quad * 4 + rr;
        O[(size_t)row * DD + h * HD + sub * 16 + l15] = f2bf(oacc[g][sub][rr] * linv[g][rr]);
      }
}

// ---------------------------------------------------------------------------
// Memory plan. ws (32 MiB): [wsA: 24 MiB = 12M sh][wsB: 8 MiB = 4M sh].
// d_out (16 MiB = 8M sh) as scratch, all regions dead before g6's overwrite:
//   cvt: w_out_l->dob+0 (1M), w_in_g->dob+1M (3M), w_in_l->dob+4M (3M), x->wsB
//   g1 : xbf(wsB) * wbf_in_l -> QKV1 @ wsA
//   al : QKV1 -> O1 @ dob+4M            (wbf_in_l dead)
//   g3 : O1 * wbf_out_l -> loc2 @ wsB   (xbf dead)
//   g4 : loc2 * wbf_in_g -> QKV2 @ wsA  (QKV1 dead)
//   vt : QKV2.V -> VT @ dob+0..4M       (wbf_out_l, wbf_in_g dead)
//   ag : QKV2.QK + VT -> O2 @ wsB       (loc2 dead)
//   cvtg: w_out_g -> wbf @ wsA          (QKV2 dead)
//   g6 : O2 * wbf_out_g -> d_out (f32)  (VT/dob scratch dead)
// ---------------------------------------------------------------------------
extern "C" void kernel_launch(void* const* d_in, const int* in_sizes, int n_in,
                              void* d_out, int out_size, void* d_ws, size_t ws_size,
                              hipStream_t stream) {
  const float* x       = (const float*)d_in[0];
  const float* w_in_l  = (const float*)d_in[1];
  const float* b_in_l  = (const float*)d_in[2];
  const float* w_out_l = (const float*)d_in[3];
  const float* b_out_l = (const float*)d_in[4];
  const float* w_in_g  = (const float*)d_in[5];
  const float* b_in_g  = (const float*)d_in[6];
  const float* w_out_g = (const float*)d_in[7];
  const float* b_out_g = (const float*)d_in[8];

  unsigned short* wsA = (unsigned short*)d_ws;            // 12M shorts
  unsigned short* wsB = wsA + (size_t)MM * TD;            // 4M shorts
  unsigned short* dob = (unsigned short*)d_out;           // 8M shorts
  unsigned short* wbf_out_l = dob;                        // 1M sh
  unsigned short* wbf_in_g  = dob + (size_t)DD * DD;      // 3M sh
  unsigned short* wbf_in_l  = dob + 4 * (size_t)DD * DD;  // 3M sh
  unsigned short* o1        = dob + 4 * (size_t)DD * DD;  // 4M sh (after g1)
  unsigned short* vtbuf     = dob;                        // 4M sh (after g4)

  dim3 blk(256);
  cvt_bf16<<<dim3(DD * DD / 2048), blk, 0, stream>>>(w_out_l, wbf_out_l, DD * DD);
  cvt_bf16<<<dim3(TD * DD / 2048), blk, 0, stream>>>(w_in_g, wbf_in_g, TD * DD);
  cvt_bf16<<<dim3(TD * DD / 2048), blk, 0, stream>>>(w_in_l, wbf_in_l, TD * DD);
  cvt_bf16<<<dim3(MM * DD / 2048), blk, 0, stream>>>(x, wsB, MM * DD);

  // 1) QKV1 = x @ w_in_l^T + b_in_l
  gemm_bt_bias<0, 0><<<dim3(TD / 128, MM / 128), blk, 0, stream>>>(wsB, wbf_in_l, b_in_l, wsA, MM, TD, DD);
  // 2) local attention (rows pre-permuted for the reshape trick)
  attn_local<<<dim3(BB * CS * HH / 4), blk, 0, stream>>>(wsA, o1);
  // 3) loc2 = O1 @ w_out_l^T + b_out_l
  gemm_bt_bias<0, 0><<<dim3(DD / 128, MM / 128), blk, 0, stream>>>(o1, wbf_out_l, b_out_l, wsB, MM, DD, DD);
  // 4) QKV2 = loc2 @ w_in_g^T + b_in_g
  gemm_bt_bias<0, 0><<<dim3(TD / 128, MM / 128), blk, 0, stream>>>(wsB, wbf_in_g, b_in_g, wsA, MM, TD, DD);
  // 5a) V pre-transpose
  transpose_v<<<dim3(BB * HH, SS / 64), blk, 0, stream>>>(wsA, vtbuf);
  // 5b) global attention (barrier-free, direct-global K/VT frags)
  attn_global<<<dim3(BB * HH, SS / 128), blk, 0, stream>>>(wsA, wsA + DD, vtbuf, wsB);
  // 5c) convert w_out_g into dead QKV2 space
  cvt_bf16<<<dim3(DD * DD / 2048), blk, 0, stream>>>(w_out_g, wsA, DD * DD);
  // 6) out = O2 @ w_out_g^T + b_out_g  (f32 out)
  gemm_bt_bias<0, 1><<<dim3(DD / 128, MM / 128), blk, 0, stream>>>(wsB, wsA, b_out_g, d_out, MM, DD, DD);
}

// Round 8
// 334.929 us; speedup vs baseline: 1.1525x; 1.1525x over previous
//
#include <hip/hip_runtime.h>

// Problem constants
#define BB 2
#define SS 2048
#define DD 1024
#define HH 16
#define HD 64
#define CS 512
#define NC 4
#define TD 3072            // 3*D
#define MM 4096            // B*S tokens

typedef __attribute__((ext_vector_type(8))) short short8;
typedef __attribute__((ext_vector_type(4))) float floatx4;

__device__ __forceinline__ float bf2f(unsigned short h) {
  union { unsigned int u; float f; } v; v.u = ((unsigned int)h) << 16; return v.f;
}
__device__ __forceinline__ unsigned short f2bf(float f) {
  union { float f; unsigned int u; } v; v.f = f;
  unsigned int r = (v.u + 0x7fffu + ((v.u >> 16) & 1u)) >> 16;
  return (unsigned short)r;
}
__device__ __forceinline__ short8 ld8f(const float* p) {
  floatx4 f0 = *(const floatx4*)p;
  floatx4 f1 = *(const floatx4*)(p + 4);
  short8 o;
  o[0] = (short)f2bf(f0[0]); o[1] = (short)f2bf(f0[1]);
  o[2] = (short)f2bf(f0[2]); o[3] = (short)f2bf(f0[3]);
  o[4] = (short)f2bf(f1[0]); o[5] = (short)f2bf(f1[1]);
  o[6] = (short)f2bf(f1[2]); o[7] = (short)f2bf(f1[3]);
  return o;
}
// exact bf16 *= 0.125 (exponent shift; RNE of exact value)
__device__ __forceinline__ short8 scale8_eighth(short8 a) {
  short8 o;
#pragma unroll
  for (int j = 0; j < 8; ++j) o[j] = (short)f2bf(bf2f((unsigned short)a[j]) * 0.125f);
  return o;
}
__device__ __forceinline__ void async16(const void* g, void* l) {
  __builtin_amdgcn_global_load_lds((const __attribute__((address_space(1))) void*)g,
                                   (__attribute__((address_space(3))) void*)l, 16, 0, 0);
}

// ---------------------------------------------------------------------------
// f32 -> bf16 convert (8 elems/thread)
// ---------------------------------------------------------------------------
__global__ __launch_bounds__(256) void cvt_bf16(const float* __restrict__ in,
                                                unsigned short* __restrict__ out, int n) {
  int i = (blockIdx.x * 256 + threadIdx.x) * 8;
  if (i < n) *(short8*)(out + i) = ld8f(in + i);
}

// ---------------------------------------------------------------------------
// GEMM: C[M,N] = A[M,K] * W[N,K]^T + bias[N]. A bf16 (global_load_lds);
// W bf16 (global_load_lds) or f32 (ld8f + ds_write). C f32 or bf16.
// 128x128 tile, BK=32, 256 threads (4 waves 2x2), m97-style staging.
// ---------------------------------------------------------------------------
template <int W_F32, int C_F32>
__global__ __launch_bounds__(256) void gemm_bt_bias(
    const unsigned short* __restrict__ A, const void* __restrict__ Wv,
    const float* __restrict__ bias, void* __restrict__ Cv, int M, int N, int K) {
  __shared__ unsigned short sA[128 * 32];
  __shared__ unsigned short sB[128 * 32];
  const int tid = threadIdx.x;
  const int wid = tid >> 6, lane = tid & 63;
  const int quad = lane >> 4, l15 = lane & 15;
  const int wm = wid & 1, wn = wid >> 1;
  const int bm = blockIdx.y, bn = blockIdx.x;

  floatx4 acc[4][4];
#pragma unroll
  for (int i = 0; i < 4; ++i)
#pragma unroll
    for (int j = 0; j < 4; ++j) acc[i][j] = (floatx4){0.f, 0.f, 0.f, 0.f};

  const int r = tid >> 2;            // 0..63
  const int kc = (tid & 3) * 8;      // 0,8,16,24
  const unsigned short* gA = A + (size_t)(bm * 128 + r) * K + kc;
  const float*          gWf = (const float*)Wv          + (size_t)(bn * 128 + r) * K + kc;
  const unsigned short* gWh = (const unsigned short*)Wv + (size_t)(bn * 128 + r) * K + kc;
  unsigned short* lA = sA + wid * 512;  // wave-uniform base; HW appends lane*16B
  unsigned short* lB = sB + wid * 512;

  for (int k0 = 0; k0 < K; k0 += 32) {
    async16(gA + k0, lA);
    async16(gA + (size_t)64 * K + k0, lA + 2048);
    if (W_F32) {
      short8 b0 = ld8f(gWf + k0);
      short8 b1 = ld8f(gWf + (size_t)64 * K + k0);
      *(short8*)(sB + r * 32 + kc) = b0;
      *(short8*)(sB + (64 + r) * 32 + kc) = b1;
    } else {
      async16(gWh + k0, lB);
      async16(gWh + (size_t)64 * K + k0, lB + 2048);
    }
    __syncthreads();

    short8 af[4], bfr[4];
#pragma unroll
    for (int i = 0; i < 4; ++i)
      af[i] = *(const short8*)(sA + (wm * 64 + i * 16 + l15) * 32 + quad * 8);
#pragma unroll
    for (int j = 0; j < 4; ++j)
      bfr[j] = *(const short8*)(sB + (wn * 64 + j * 16 + l15) * 32 + quad * 8);
#pragma unroll
    for (int i = 0; i < 4; ++i)
#pragma unroll
      for (int j = 0; j < 4; ++j)
        acc[i][j] = __builtin_amdgcn_mfma_f32_16x16x32_bf16(af[i], bfr[j], acc[i][j], 0, 0, 0);
    __syncthreads();
  }

  // Epilogue. C/D layout: col = lane&15, row = quad*4 + reg.
#pragma unroll
  for (int j = 0; j < 4; ++j) {
    int n = bn * 128 + wn * 64 + j * 16 + l15;
    float bv = bias[n];
#pragma unroll
    for (int i = 0; i < 4; ++i) {
      int mrow = bm * 128 + wm * 64 + i * 16 + quad * 4;
#pragma unroll
      for (int rr = 0; rr < 4; ++rr) {
        float v = acc[i][j][rr] + bv;
        if (C_F32) ((float*)Cv)[(size_t)(mrow + rr) * N + n] = v;
        else ((unsigned short*)Cv)[(size_t)(mrow + rr) * N + n] = f2bf(v);
      }
    }
  }
}

// ---------------------------------------------------------------------------
// Local attention: seq len nc=4 across chunks, one wave per (b,c,h).
// Reads packed QKV1 (bf16, stride TD) rows t1=b*2048+n*512+c; writes O1
// (bf16, stride DD) rows permuted t2=n*1024+b*512+c.
// ---------------------------------------------------------------------------
__global__ __launch_bounds__(256) void attn_local(const unsigned short* __restrict__ QKV,
                                                  unsigned short* __restrict__ O) {
  const int tid = threadIdx.x;
  const int wid = tid >> 6, lane = tid & 63;
  const int idx = blockIdx.x * 4 + wid;  // (b*512 + c)*16 + h
  const int h = idx & 15, c = (idx >> 4) & 511, b = idx >> 13;

  float q[NC], k[NC], v[NC];
#pragma unroll
  for (int n = 0; n < NC; ++n) {
    size_t base = (size_t)(b * SS + n * CS + c) * TD + h * HD + lane;
    q[n] = bf2f(QKV[base]);
    k[n] = bf2f(QKV[base + DD]);
    v[n] = bf2f(QKV[base + 2 * DD]);
  }
  float s[NC][NC];
#pragma unroll
  for (int m = 0; m < NC; ++m)
#pragma unroll
    for (int n = 0; n < NC; ++n) {
      float p = q[m] * k[n];
#pragma unroll
      for (int off = 32; off >= 1; off >>= 1) p += __shfl_xor(p, off);
      s[m][n] = p * 0.125f;
    }
#pragma unroll
  for (int m = 0; m < NC; ++m) {
    float mx = fmaxf(fmaxf(s[m][0], s[m][1]), fmaxf(s[m][2], s[m][3]));
    float e[NC], sum = 0.f;
#pragma unroll
    for (int n = 0; n < NC; ++n) { e[n] = __expf(s[m][n] - mx); sum += e[n]; }
    float o = (e[0] * v[0] + e[1] * v[1] + e[2] * v[2] + e[3] * v[3]) / sum;
    O[(size_t)(m * (BB * CS) + b * CS + c) * DD + h * HD + lane] = f2bf(o);
  }
}

// ---------------------------------------------------------------------------
// V pre-transpose: QKV2 V-columns -> VT[b][h][dim(64)][token(2048)].
// 64x64 tiles via swizzled LDS. Grid (bh=32, stile=32).
// ---------------------------------------------------------------------------
__global__ __launch_bounds__(256) void transpose_v(const unsigned short* __restrict__ QKV,
                                                   unsigned short* __restrict__ VT) {
  __shared__ unsigned short sT[64 * 64];
  const int tid = threadIdx.x;
  const int bh = blockIdx.x, b = bh >> 4, h = bh & 15;
  const int s0 = blockIdx.y * 64;
#pragma unroll
  for (int it = 0; it < 2; ++it) {
    int C = it * 256 + tid;
    int t = C >> 3, dc = C & 7;
    short8 v = *(const short8*)(QKV + (size_t)(b * SS + s0 + t) * TD + 2 * DD + h * HD + dc * 8);
    *(short8*)(sT + t * 64 + ((dc ^ (t & 7)) << 3)) = v;
  }
  __syncthreads();
#pragma unroll
  for (int it = 0; it < 2; ++it) {
    int C = it * 256 + tid;
    int d = C >> 3, tc = C & 7;
    short8 o;
#pragma unroll
    for (int j = 0; j < 8; ++j) {
      int t = tc * 8 + j;
      o[j] = (short)sT[t * 64 + (((d >> 3) ^ (t & 7)) << 3) + (d & 7)];
    }
    *(short8*)(VT + ((size_t)(bh * 64 + d)) * SS + s0 + tc * 8) = o;
  }
}

// ---------------------------------------------------------------------------
// Global attention (round-6 staged structure, 2 q-groups/wave):
// 128 threads = 2 waves, each wave owns 32 q-rows; 64-key tiles staged in LDS
// (swizzled, zero-conflict per round-6 counters). Streaming exp-sum with
// truncation-rounded P and bias-cancelling lsum. Grid (x=bh, y=SS/64).
// ---------------------------------------------------------------------------
__global__ __launch_bounds__(128) void attn_global(
    const unsigned short* __restrict__ Q, const unsigned short* __restrict__ Kp,
    const unsigned short* __restrict__ VT, unsigned short* __restrict__ O) {
  __shared__ unsigned short sK[64 * 64];   // [key][dim-chunk ^ (key&7)]
  __shared__ unsigned short sVT[64 * 64];  // [dim][key-chunk ^ (dim&7)]
  __shared__ unsigned short sP[2][32 * 64];
  const int tid = threadIdx.x;
  const int wid = tid >> 6, lane = tid & 63;
  const int quad = lane >> 4, l15 = lane & 15;
  const int bh = blockIdx.x;
  const int b = bh >> 4, h = bh & 15;
  const int q0 = blockIdx.y * 64 + wid * 32;

  // Q A-frags for 2 row-groups, pre-scaled by 1/8 (exact)
  short8 qf[2][2];
#pragma unroll
  for (int g = 0; g < 2; ++g) {
    const unsigned short* qr = Q + (size_t)(b * SS + q0 + g * 16 + l15) * TD + h * HD + quad * 8;
    qf[g][0] = scale8_eighth(*(const short8*)qr);
    qf[g][1] = scale8_eighth(*(const short8*)(qr + 32));
  }

  float lsum[2][4];
  floatx4 oacc[2][4];
#pragma unroll
  for (int g = 0; g < 2; ++g)
#pragma unroll
    for (int s = 0; s < 4; ++s) { lsum[g][s] = 0.f; oacc[g][s] = (floatx4){0.f, 0.f, 0.f, 0.f}; }

  unsigned short* myP = &sP[wid][0];
  const unsigned short* vbase = VT + (size_t)(bh * 64) * SS;

  for (int kt = 0; kt < SS / 64; ++kt) {
    const int kbase = kt * 64;
    // stage K tile: chunk (key, dc) -> phys chunk dc^(key&7); 128 thr, 4 iters
#pragma unroll
    for (int it = 0; it < 4; ++it) {
      int P = it * 128 + tid;
      int key = P >> 3, dc = P & 7;
      short8 kv = *(const short8*)(Kp + (size_t)(b * SS + kbase + key) * TD + h * HD + dc * 8);
      *(short8*)(sK + key * 64 + ((dc ^ (key & 7)) << 3)) = kv;
    }
    // stage V^T tile: chunk (dim, kc) -> phys chunk kc^(dim&7)
#pragma unroll
    for (int it = 0; it < 4; ++it) {
      int P = it * 128 + tid;
      int dim = P >> 3, kcc = P & 7;
      short8 vv = *(const short8*)(vbase + (size_t)dim * SS + kbase + kcc * 8);
      *(short8*)(sVT + dim * 64 + ((kcc ^ (dim & 7)) << 3)) = vv;
    }
    __syncthreads();

    // S = (Q/8) K^T (C-layout: q-row m=quad*4+rr, col key=sub*16+l15)
    floatx4 sacc[2][4];
#pragma unroll
    for (int sub = 0; sub < 4; ++sub) {
      int key = sub * 16 + l15;
      int c0 = (quad ^ (key & 7)) << 3;
      short8 kf0 = *(const short8*)(sK + key * 64 + c0);
      short8 kf1 = *(const short8*)(sK + key * 64 + (c0 ^ 32));
#pragma unroll
      for (int g = 0; g < 2; ++g) {
        floatx4 z = (floatx4){0.f, 0.f, 0.f, 0.f};
        z = __builtin_amdgcn_mfma_f32_16x16x32_bf16(qf[g][0], kf0, z, 0, 0, 0);
        z = __builtin_amdgcn_mfma_f32_16x16x32_bf16(qf[g][1], kf1, z, 0, 0, 0);
        sacc[g][sub] = z;
      }
    }

    // streaming exp; truncate to bf16 for P, accumulate the SAME truncated
    // value into lsum (systematic truncation bias cancels in the ratio)
#pragma unroll
    for (int g = 0; g < 2; ++g)
#pragma unroll
      for (int sub = 0; sub < 4; ++sub) {
        int kc8 = sub * 2 + (l15 >> 3), k7 = l15 & 7;
#pragma unroll
        for (int rr = 0; rr < 4; ++rr) {
          unsigned int u = __float_as_uint(__expf(sacc[g][sub][rr]));
          lsum[g][rr] += __uint_as_float(u & 0xffff0000u);
          int row = g * 16 + quad * 4 + rr;
          myP[row * 64 + ((kc8 ^ (row & 7)) << 3) + k7] = (unsigned short)(u >> 16);
        }
      }
    __asm__ volatile("s_waitcnt lgkmcnt(0)" ::: "memory");  // wave-private RAW

    // P A-frags (row-group g, key-chunk c)
    short8 pf[2][2];
#pragma unroll
    for (int g = 0; g < 2; ++g) {
      int row = g * 16 + l15;
      int sw = row & 7;
#pragma unroll
      for (int c = 0; c < 2; ++c)
        pf[g][c] = *(const short8*)(myP + row * 64 + (((c * 4 + quad) ^ sw) << 3));
    }

    // O += P * V  (B-frag: lane n=dim holds V[key=quad*8+j][n] = sVT[n][key])
#pragma unroll
    for (int sub = 0; sub < 4; ++sub) {
      int n = sub * 16 + l15;
      int v0 = (quad ^ (n & 7)) << 3;
      short8 vt0 = *(const short8*)(sVT + n * 64 + v0);
      short8 vt1 = *(const short8*)(sVT + n * 64 + (v0 ^ 32));
#pragma unroll
      for (int g = 0; g < 2; ++g) {
        oacc[g][sub] = __builtin_amdgcn_mfma_f32_16x16x32_bf16(pf[g][0], vt0, oacc[g][sub], 0, 0, 0);
        oacc[g][sub] = __builtin_amdgcn_mfma_f32_16x16x32_bf16(pf[g][1], vt1, oacc[g][sub], 0, 0, 0);
      }
    }
    __syncthreads();
  }

  // lsum reduce across the quad's 16 lanes, then normalize & store (RNE)
  float linv[2][4];
#pragma unroll
  for (int g = 0; g < 2; ++g)
#pragma unroll
    for (int rr = 0; rr < 4; ++rr) {
      float t = lsum[g][rr];
#pragma unroll
      for (int off = 8; off >= 1; off >>= 1) t += __shfl_xor(t, off);
      linv[g][rr] = 1.f / t;
    }
#pragma unroll
  for (int g = 0; g < 2; ++g)
#pragma unroll
    for (int sub = 0; sub < 4; ++sub)
#pragma unroll
      for (int rr = 0; rr < 4; ++rr) {
        int row = b * SS + q0 + g * 16 + quad * 4 + rr;
        O[(size_t)row * DD + h * HD + sub * 16 + l15] = f2bf(oacc[g][sub][rr] * linv[g][rr]);
      }
}

// ---------------------------------------------------------------------------
// Memory plan. ws (32 MiB): [wsA: 24 MiB = 12M sh][wsB: 8 MiB = 4M sh].
// d_out (16 MiB = 8M sh) as scratch, all regions dead before g6's overwrite:
//   cvt: w_out_l->dob+0 (1M), w_in_g->dob+1M (3M), w_in_l->dob+4M (3M), x->wsB
//   g1 : xbf(wsB) * wbf_in_l -> QKV1 @ wsA
//   al : QKV1 -> O1 @ dob+4M            (wbf_in_l dead)
//   g3 : O1 * wbf_out_l -> loc2 @ wsB   (xbf dead)
//   g4 : loc2 * wbf_in_g -> QKV2 @ wsA  (QKV1 dead)
//   vt : QKV2.V -> VT @ dob+0..4M       (wbf_out_l, wbf_in_g dead)
//   ag : QKV2.QK + VT -> O2 @ wsB       (loc2 dead)
//   cvtg: w_out_g -> wbf @ wsA          (QKV2 dead)
//   g6 : O2 * wbf_out_g -> d_out (f32)  (VT/dob scratch dead)
// ---------------------------------------------------------------------------
extern "C" void kernel_launch(void* const* d_in, const int* in_sizes, int n_in,
                              void* d_out, int out_size, void* d_ws, size_t ws_size,
                              hipStream_t stream) {
  const float* x       = (const float*)d_in[0];
  const float* w_in_l  = (const float*)d_in[1];
  const float* b_in_l  = (const float*)d_in[2];
  const float* w_out_l = (const float*)d_in[3];
  const float* b_out_l = (const float*)d_in[4];
  const float* w_in_g  = (const float*)d_in[5];
  const float* b_in_g  = (const float*)d_in[6];
  const float* w_out_g = (const float*)d_in[7];
  const float* b_out_g = (const float*)d_in[8];

  unsigned short* wsA = (unsigned short*)d_ws;            // 12M shorts
  unsigned short* wsB = wsA + (size_t)MM * TD;            // 4M shorts
  unsigned short* dob = (unsigned short*)d_out;           // 8M shorts
  unsigned short* wbf_out_l = dob;                        // 1M sh
  unsigned short* wbf_in_g  = dob + (size_t)DD * DD;      // 3M sh
  unsigned short* wbf_in_l  = dob + 4 * (size_t)DD * DD;  // 3M sh
  unsigned short* o1        = dob + 4 * (size_t)DD * DD;  // 4M sh (after g1)
  unsigned short* vtbuf     = dob;                        // 4M sh (after g4)

  dim3 blk(256);
  cvt_bf16<<<dim3(DD * DD / 2048), blk, 0, stream>>>(w_out_l, wbf_out_l, DD * DD);
  cvt_bf16<<<dim3(TD * DD / 2048), blk, 0, stream>>>(w_in_g, wbf_in_g, TD * DD);
  cvt_bf16<<<dim3(TD * DD / 2048), blk, 0, stream>>>(w_in_l, wbf_in_l, TD * DD);
  cvt_bf16<<<dim3(MM * DD / 2048), blk, 0, stream>>>(x, wsB, MM * DD);

  // 1) QKV1 = x @ w_in_l^T + b_in_l
  gemm_bt_bias<0, 0><<<dim3(TD / 128, MM / 128), blk, 0, stream>>>(wsB, wbf_in_l, b_in_l, wsA, MM, TD, DD);
  // 2) local attention (rows pre-permuted for the reshape trick)
  attn_local<<<dim3(BB * CS * HH / 4), blk, 0, stream>>>(wsA, o1);
  // 3) loc2 = O1 @ w_out_l^T + b_out_l
  gemm_bt_bias<0, 0><<<dim3(DD / 128, MM / 128), blk, 0, stream>>>(o1, wbf_out_l, b_out_l, wsB, MM, DD, DD);
  // 4) QKV2 = loc2 @ w_in_g^T + b_in_g
  gemm_bt_bias<0, 0><<<dim3(TD / 128, MM / 128), blk, 0, stream>>>(wsB, wbf_in_g, b_in_g, wsA, MM, TD, DD);
  // 5a) V pre-transpose
  transpose_v<<<dim3(BB * HH, SS / 64), blk, 0, stream>>>(wsA, vtbuf);
  // 5b) global attention (staged LDS, 2 q-groups/wave, 2-wave blocks)
  attn_global<<<dim3(BB * HH, SS / 64), dim3(128), 0, stream>>>(wsA, wsA + DD, vtbuf, wsB);
  // 5c) convert w_out_g into dead QKV2 space
  cvt_bf16<<<dim3(DD * DD / 2048), blk, 0, stream>>>(w_out_g, wsA, DD * DD);
  // 6) out = O2 @ w_out_g^T + b_out_g  (f32 out)
  gemm_bt_bias<0, 1><<<dim3(DD / 128, MM / 128), blk, 0, stream>>>(wsB, wsA, b_out_g, d_out, MM, DD, DD);
}

// Round 9
// 326.590 us; speedup vs baseline: 1.1819x; 1.0255x over previous
//
#include <hip/hip_runtime.h>

// Problem constants
#define BB 2
#define SS 2048
#define DD 1024
#define HH 16
#define HD 64
#define CS 512
#define NC 4
#define TD 3072            // 3*D
#define MM 4096            // B*S tokens

typedef __attribute__((ext_vector_type(8))) short short8;
typedef __attribute__((ext_vector_type(4))) float floatx4;

__device__ __forceinline__ float bf2f(unsigned short h) {
  union { unsigned int u; float f; } v; v.u = ((unsigned int)h) << 16; return v.f;
}
__device__ __forceinline__ unsigned short f2bf(float f) {
  union { float f; unsigned int u; } v; v.f = f;
  unsigned int r = (v.u + 0x7fffu + ((v.u >> 16) & 1u)) >> 16;
  return (unsigned short)r;
}
__device__ __forceinline__ short8 ld8f(const float* p) {
  floatx4 f0 = *(const floatx4*)p;
  floatx4 f1 = *(const floatx4*)(p + 4);
  short8 o;
  o[0] = (short)f2bf(f0[0]); o[1] = (short)f2bf(f0[1]);
  o[2] = (short)f2bf(f0[2]); o[3] = (short)f2bf(f0[3]);
  o[4] = (short)f2bf(f1[0]); o[5] = (short)f2bf(f1[1]);
  o[6] = (short)f2bf(f1[2]); o[7] = (short)f2bf(f1[3]);
  return o;
}
// exact bf16 *= 0.125 (exponent shift; RNE of exact value)
__device__ __forceinline__ short8 scale8_eighth(short8 a) {
  short8 o;
#pragma unroll
  for (int j = 0; j < 8; ++j) o[j] = (short)f2bf(bf2f((unsigned short)a[j]) * 0.125f);
  return o;
}
__device__ __forceinline__ void async16(const void* g, void* l) {
  __builtin_amdgcn_global_load_lds((const __attribute__((address_space(1))) void*)g,
                                   (__attribute__((address_space(3))) void*)l, 16, 0, 0);
}

// ---------------------------------------------------------------------------
// Fused f32 -> bf16 convert for 4 segments (sizes in 2048-elem blocks)
// ---------------------------------------------------------------------------
__global__ __launch_bounds__(256) void cvt_all(
    const float* __restrict__ s0, unsigned short* __restrict__ d0, int n0,
    const float* __restrict__ s1, unsigned short* __restrict__ d1, int n1,
    const float* __restrict__ s2, unsigned short* __restrict__ d2, int n2,
    const float* __restrict__ s3, unsigned short* __restrict__ d3, int n3) {
  int bb = blockIdx.x;
  const float* s; unsigned short* d; int off;
  if (bb < n0) { s = s0; d = d0; off = bb; }
  else if (bb < n0 + n1) { s = s1; d = d1; off = bb - n0; }
  else if (bb < n0 + n1 + n2) { s = s2; d = d2; off = bb - n0 - n1; }
  else { s = s3; d = d3; off = bb - n0 - n1 - n2; }
  int i = (off * 256 + threadIdx.x) * 8;
  *(short8*)(d + i) = ld8f(s + i);
}

__global__ __launch_bounds__(256) void cvt_bf16(const float* __restrict__ in,
                                                unsigned short* __restrict__ out, int n) {
  int i = (blockIdx.x * 256 + threadIdx.x) * 8;
  if (i < n) *(short8*)(out + i) = ld8f(in + i);
}

// ---------------------------------------------------------------------------
// GEMM: C[M,N] = A[M,K] * W[N,K]^T + bias[N]. bf16 in (global_load_lds),
// C f32 or bf16. MT x 128 tile (MT=128 or 64), BK=32, 256 threads (2x2 waves).
// ---------------------------------------------------------------------------
template <int MT, int C_F32>
__global__ __launch_bounds__(256) void gemm_bt_bias(
    const unsigned short* __restrict__ A, const unsigned short* __restrict__ W,
    const float* __restrict__ bias, void* __restrict__ Cv, int M, int N, int K) {
  constexpr int AI = MT / 32;  // A-frags per wave
  __shared__ unsigned short sA[MT * 32];
  __shared__ unsigned short sB[128 * 32];
  const int tid = threadIdx.x;
  const int wid = tid >> 6, lane = tid & 63;
  const int quad = lane >> 4, l15 = lane & 15;
  const int wm = wid & 1, wn = wid >> 1;
  const int bm = blockIdx.y, bn = blockIdx.x;

  floatx4 acc[AI][4];
#pragma unroll
  for (int i = 0; i < AI; ++i)
#pragma unroll
    for (int j = 0; j < 4; ++j) acc[i][j] = (floatx4){0.f, 0.f, 0.f, 0.f};

  const int r = tid >> 2;            // 0..63
  const int kc = (tid & 3) * 8;      // 0,8,16,24
  const unsigned short* gA = A + (size_t)(bm * MT + r) * K + kc;
  const unsigned short* gW = W + (size_t)(bn * 128 + r) * K + kc;
  unsigned short* lA = sA + wid * 512;  // wave-uniform base; HW appends lane*16B
  unsigned short* lB = sB + wid * 512;

  for (int k0 = 0; k0 < K; k0 += 32) {
#pragma unroll
    for (int s = 0; s < MT / 64; ++s)
      async16(gA + (size_t)(s * 64) * K + k0, lA + s * 2048);
    async16(gW + k0, lB);
    async16(gW + (size_t)64 * K + k0, lB + 2048);
    __syncthreads();

    short8 af[AI], bfr[4];
#pragma unroll
    for (int i = 0; i < AI; ++i)
      af[i] = *(const short8*)(sA + (wm * (MT / 2) + i * 16 + l15) * 32 + quad * 8);
#pragma unroll
    for (int j = 0; j < 4; ++j)
      bfr[j] = *(const short8*)(sB + (wn * 64 + j * 16 + l15) * 32 + quad * 8);
#pragma unroll
    for (int i = 0; i < AI; ++i)
#pragma unroll
      for (int j = 0; j < 4; ++j)
        acc[i][j] = __builtin_amdgcn_mfma_f32_16x16x32_bf16(af[i], bfr[j], acc[i][j], 0, 0, 0);
    __syncthreads();
  }

  // Epilogue. C/D layout: col = lane&15, row = quad*4 + reg.
#pragma unroll
  for (int j = 0; j < 4; ++j) {
    int n = bn * 128 + wn * 64 + j * 16 + l15;
    float bv = bias[n];
#pragma unroll
    for (int i = 0; i < AI; ++i) {
      int mrow = bm * MT + wm * (MT / 2) + i * 16 + quad * 4;
#pragma unroll
      for (int rr = 0; rr < 4; ++rr) {
        float v = acc[i][j][rr] + bv;
        if (C_F32) ((float*)Cv)[(size_t)(mrow + rr) * N + n] = v;
        else ((unsigned short*)Cv)[(size_t)(mrow + rr) * N + n] = f2bf(v);
      }
    }
  }
}

// ---------------------------------------------------------------------------
// Local attention: seq len nc=4 across chunks, one wave per (b,c,h).
// Reads packed QKV1 (bf16, stride TD) rows t1=b*2048+n*512+c; writes O1
// (bf16, stride DD) rows permuted t2=n*1024+b*512+c.
// ---------------------------------------------------------------------------
__global__ __launch_bounds__(256) void attn_local(const unsigned short* __restrict__ QKV,
                                                  unsigned short* __restrict__ O) {
  const int tid = threadIdx.x;
  const int wid = tid >> 6, lane = tid & 63;
  const int idx = blockIdx.x * 4 + wid;  // (b*512 + c)*16 + h
  const int h = idx & 15, c = (idx >> 4) & 511, b = idx >> 13;

  float q[NC], k[NC], v[NC];
#pragma unroll
  for (int n = 0; n < NC; ++n) {
    size_t base = (size_t)(b * SS + n * CS + c) * TD + h * HD + lane;
    q[n] = bf2f(QKV[base]);
    k[n] = bf2f(QKV[base + DD]);
    v[n] = bf2f(QKV[base + 2 * DD]);
  }
  float s[NC][NC];
#pragma unroll
  for (int m = 0; m < NC; ++m)
#pragma unroll
    for (int n = 0; n < NC; ++n) {
      float p = q[m] * k[n];
#pragma unroll
      for (int off = 32; off >= 1; off >>= 1) p += __shfl_xor(p, off);
      s[m][n] = p * 0.125f;
    }
#pragma unroll
  for (int m = 0; m < NC; ++m) {
    float mx = fmaxf(fmaxf(s[m][0], s[m][1]), fmaxf(s[m][2], s[m][3]));
    float e[NC], sum = 0.f;
#pragma unroll
    for (int n = 0; n < NC; ++n) { e[n] = __expf(s[m][n] - mx); sum += e[n]; }
    float o = (e[0] * v[0] + e[1] * v[1] + e[2] * v[2] + e[3] * v[3]) / sum;
    O[(size_t)(m * (BB * CS) + b * CS + c) * DD + h * HD + lane] = f2bf(o);
  }
}

// ---------------------------------------------------------------------------
// V pre-transpose: QKV2 V-columns -> VT[b][h][dim(64)][token(2048)].
// 64x64 tiles via swizzled LDS. Grid (bh=32, stile=32).
// ---------------------------------------------------------------------------
__global__ __launch_bounds__(256) void transpose_v(const unsigned short* __restrict__ QKV,
                                                   unsigned short* __restrict__ VT) {
  __shared__ unsigned short sT[64 * 64];
  const int tid = threadIdx.x;
  const int bh = blockIdx.x, b = bh >> 4, h = bh & 15;
  const int s0 = blockIdx.y * 64;
#pragma unroll
  for (int it = 0; it < 2; ++it) {
    int C = it * 256 + tid;
    int t = C >> 3, dc = C & 7;
    short8 v = *(const short8*)(QKV + (size_t)(b * SS + s0 + t) * TD + 2 * DD + h * HD + dc * 8);
    *(short8*)(sT + t * 64 + ((dc ^ (t & 7)) << 3)) = v;
  }
  __syncthreads();
#pragma unroll
  for (int it = 0; it < 2; ++it) {
    int C = it * 256 + tid;
    int d = C >> 3, tc = C & 7;
    short8 o;
#pragma unroll
    for (int j = 0; j < 8; ++j) {
      int t = tc * 8 + j;
      o[j] = (short)sT[t * 64 + (((d >> 3) ^ (t & 7)) << 3) + (d & 7)];
    }
    *(short8*)(VT + ((size_t)(bh * 64 + d)) * SS + s0 + tc * 8) = o;
  }
}

// ---------------------------------------------------------------------------
// Global attention with in-block K-split: 256 thr = 4 waves; block owns 64
// q-rows; wave (qhalf=wid&1, khalf=wid>>1) does 32 q x 1024 keys. Both khalf
// tiles staged per step (swizzled, zero-conflict). Streaming exp-sum
// (truncation-rounded P, bias-cancelling lsum); partials merged via LDS at
// the end (exact: max-free softmax is additive). Grid (x=bh, y=SS/64).
// ---------------------------------------------------------------------------
__global__ __launch_bounds__(256) void attn_global(
    const unsigned short* __restrict__ Q, const unsigned short* __restrict__ Kp,
    const unsigned short* __restrict__ VT, unsigned short* __restrict__ O) {
  __shared__ unsigned short sK[2][64 * 64];   // [khalf][key][dim-chunk ^ (key&7)]
  __shared__ unsigned short sVT[2][64 * 64];  // [khalf][dim][key-chunk ^ (dim&7)]
  __shared__ unsigned short sP[4][32 * 64];   // wave-private P; reused as f32 merge buf
  __shared__ float lsumBuf[64];
  const int tid = threadIdx.x;
  const int wid = tid >> 6, lane = tid & 63;
  const int quad = lane >> 4, l15 = lane & 15;
  const int qhalf = wid & 1, khalf = wid >> 1;
  const int bh = blockIdx.x;
  const int b = bh >> 4, h = bh & 15;
  const int q0 = blockIdx.y * 64 + qhalf * 32;

  // Q A-frags for 2 row-groups, pre-scaled by 1/8 (exact)
  short8 qf[2][2];
#pragma unroll
  for (int g = 0; g < 2; ++g) {
    const unsigned short* qr = Q + (size_t)(b * SS + q0 + g * 16 + l15) * TD + h * HD + quad * 8;
    qf[g][0] = scale8_eighth(*(const short8*)qr);
    qf[g][1] = scale8_eighth(*(const short8*)(qr + 32));
  }

  float lsum[2][4];
  floatx4 oacc[2][4];
#pragma unroll
  for (int g = 0; g < 2; ++g)
#pragma unroll
    for (int s = 0; s < 4; ++s) { lsum[g][s] = 0.f; oacc[g][s] = (floatx4){0.f, 0.f, 0.f, 0.f}; }

  unsigned short* myP = &sP[wid][0];
  const unsigned short* myK = &sK[khalf][0];
  const unsigned short* myV = &sVT[khalf][0];
  const unsigned short* vbase = VT + (size_t)(bh * 64) * SS;

  for (int t = 0; t < 16; ++t) {
    // stage both khalf tiles (keys kh*1024 + t*64 .. +64)
#pragma unroll
    for (int kh = 0; kh < 2; ++kh) {
      const int kbase = (kh * 16 + t) * 64;
#pragma unroll
      for (int it = 0; it < 2; ++it) {
        int P = it * 256 + tid;
        int key = P >> 3, dc = P & 7;
        short8 kv = *(const short8*)(Kp + (size_t)(b * SS + kbase + key) * TD + h * HD + dc * 8);
        *(short8*)(&sK[kh][0] + key * 64 + ((dc ^ (key & 7)) << 3)) = kv;
      }
#pragma unroll
      for (int it = 0; it < 2; ++it) {
        int P = it * 256 + tid;
        int dim = P >> 3, kcc = P & 7;
        short8 vv = *(const short8*)(vbase + (size_t)dim * SS + kbase + kcc * 8);
        *(short8*)(&sVT[kh][0] + dim * 64 + ((kcc ^ (dim & 7)) << 3)) = vv;
      }
    }
    __syncthreads();

    // S = (Q/8) K^T (C-layout: q-row m=quad*4+rr, col key=sub*16+l15)
    floatx4 sacc[2][4];
#pragma unroll
    for (int sub = 0; sub < 4; ++sub) {
      int key = sub * 16 + l15;
      int c0 = (quad ^ (key & 7)) << 3;
      short8 kf0 = *(const short8*)(myK + key * 64 + c0);
      short8 kf1 = *(const short8*)(myK + key * 64 + (c0 ^ 32));
#pragma unroll
      for (int g = 0; g < 2; ++g) {
        floatx4 z = (floatx4){0.f, 0.f, 0.f, 0.f};
        z = __builtin_amdgcn_mfma_f32_16x16x32_bf16(qf[g][0], kf0, z, 0, 0, 0);
        z = __builtin_amdgcn_mfma_f32_16x16x32_bf16(qf[g][1], kf1, z, 0, 0, 0);
        sacc[g][sub] = z;
      }
    }

    // streaming exp; truncate to bf16 for P, accumulate the SAME truncated
    // value into lsum (systematic truncation bias cancels in the ratio)
#pragma unroll
    for (int g = 0; g < 2; ++g)
#pragma unroll
      for (int sub = 0; sub < 4; ++sub) {
        int kc8 = sub * 2 + (l15 >> 3), k7 = l15 & 7;
#pragma unroll
        for (int rr = 0; rr < 4; ++rr) {
          unsigned int u = __float_as_uint(__expf(sacc[g][sub][rr]));
          lsum[g][rr] += __uint_as_float(u & 0xffff0000u);
          int row = g * 16 + quad * 4 + rr;
          myP[row * 64 + ((kc8 ^ (row & 7)) << 3) + k7] = (unsigned short)(u >> 16);
        }
      }
    __asm__ volatile("s_waitcnt lgkmcnt(0)" ::: "memory");  // wave-private RAW

    // P A-frags
    short8 pf[2][2];
#pragma unroll
    for (int g = 0; g < 2; ++g) {
      int row = g * 16 + l15;
      int sw = row & 7;
#pragma unroll
      for (int c = 0; c < 2; ++c)
        pf[g][c] = *(const short8*)(myP + row * 64 + (((c * 4 + quad) ^ sw) << 3));
    }

    // O += P * V  (B-frag: lane n=dim holds V[key=quad*8+j][n] = sVT[n][key])
#pragma unroll
    for (int sub = 0; sub < 4; ++sub) {
      int n = sub * 16 + l15;
      int v0 = (quad ^ (n & 7)) << 3;
      short8 vt0 = *(const short8*)(myV + n * 64 + v0);
      short8 vt1 = *(const short8*)(myV + n * 64 + (v0 ^ 32));
#pragma unroll
      for (int g = 0; g < 2; ++g) {
        oacc[g][sub] = __builtin_amdgcn_mfma_f32_16x16x32_bf16(pf[g][0], vt0, oacc[g][sub], 0, 0, 0);
        oacc[g][sub] = __builtin_amdgcn_mfma_f32_16x16x32_bf16(pf[g][1], vt1, oacc[g][sub], 0, 0, 0);
      }
    }
    __syncthreads();
  }

  // in-wave lsum reduce across the quad's 16 lanes
  float lred[2][4];
#pragma unroll
  for (int g = 0; g < 2; ++g)
#pragma unroll
    for (int rr = 0; rr < 4; ++rr) {
      float t = lsum[g][rr];
#pragma unroll
      for (int off = 8; off >= 1; off >>= 1) t += __shfl_xor(t, off);
      lred[g][rr] = t;
    }

  // cross-khalf merge via LDS (sP reused as f32 buffer: qhalf*2048 region)
  float* obuf = (float*)&sP[0][0];
  if (khalf == 1) {
    float* my = obuf + qhalf * 2048;
#pragma unroll
    for (int g = 0; g < 2; ++g)
#pragma unroll
      for (int sub = 0; sub < 4; ++sub)
#pragma unroll
        for (int rr = 0; rr < 4; ++rr)
          my[(g * 16 + quad * 4 + rr) * 64 + sub * 16 + l15] = oacc[g][sub][rr];
    if (l15 == 0)
#pragma unroll
      for (int g = 0; g < 2; ++g)
#pragma unroll
        for (int rr = 0; rr < 4; ++rr)
          lsumBuf[qhalf * 32 + g * 16 + quad * 4 + rr] = lred[g][rr];
  }
  __syncthreads();
  if (khalf == 0) {
    float* my = obuf + qhalf * 2048;
#pragma unroll
    for (int g = 0; g < 2; ++g) {
#pragma unroll
      for (int rr = 0; rr < 4; ++rr)
        lred[g][rr] = 1.f / (lred[g][rr] + lsumBuf[qhalf * 32 + g * 16 + quad * 4 + rr]);
#pragma unroll
      for (int sub = 0; sub < 4; ++sub)
#pragma unroll
        for (int rr = 0; rr < 4; ++rr) {
          float v = oacc[g][sub][rr] + my[(g * 16 + quad * 4 + rr) * 64 + sub * 16 + l15];
          int row = b * SS + q0 + g * 16 + quad * 4 + rr;
          O[(size_t)row * DD + h * HD + sub * 16 + l15] = f2bf(v * lred[g][rr]);
        }
    }
  }
}

// ---------------------------------------------------------------------------
// Memory plan. ws (32 MiB): [wsA: 24 MiB = 12M sh][wsB: 8 MiB = 4M sh].
// d_out (16 MiB = 8M sh) as scratch, all regions dead before g6's overwrite:
//   cvt: w_out_l->dob+0 (1M), w_in_g->dob+1M (3M), w_in_l->dob+4M (3M), x->wsB
//   g1 : xbf(wsB) * wbf_in_l -> QKV1 @ wsA
//   al : QKV1 -> O1 @ dob+4M            (wbf_in_l dead)
//   g3 : O1 * wbf_out_l -> loc2 @ wsB   (xbf dead)
//   g4 : loc2 * wbf_in_g -> QKV2 @ wsA  (QKV1 dead)
//   vt : QKV2.V -> VT @ dob+0..4M       (wbf_out_l, wbf_in_g dead)
//   ag : QKV2.QK + VT -> O2 @ wsB       (loc2 dead)
//   cvtg: w_out_g -> wbf @ wsA          (QKV2 dead)
//   g6 : O2 * wbf_out_g -> d_out (f32)  (VT/dob scratch dead)
// ---------------------------------------------------------------------------
extern "C" void kernel_launch(void* const* d_in, const int* in_sizes, int n_in,
                              void* d_out, int out_size, void* d_ws, size_t ws_size,
                              hipStream_t stream) {
  const float* x       = (const float*)d_in[0];
  const float* w_in_l  = (const float*)d_in[1];
  const float* b_in_l  = (const float*)d_in[2];
  const float* w_out_l = (const float*)d_in[3];
  const float* b_out_l = (const float*)d_in[4];
  const float* w_in_g  = (const float*)d_in[5];
  const float* b_in_g  = (const float*)d_in[6];
  const float* w_out_g = (const float*)d_in[7];
  const float* b_out_g = (const float*)d_in[8];

  unsigned short* wsA = (unsigned short*)d_ws;            // 12M shorts
  unsigned short* wsB = wsA + (size_t)MM * TD;            // 4M shorts
  unsigned short* dob = (unsigned short*)d_out;           // 8M shorts
  unsigned short* wbf_out_l = dob;                        // 1M sh
  unsigned short* wbf_in_g  = dob + (size_t)DD * DD;      // 3M sh
  unsigned short* wbf_in_l  = dob + 4 * (size_t)DD * DD;  // 3M sh
  unsigned short* o1        = dob + 4 * (size_t)DD * DD;  // 4M sh (after g1)
  unsigned short* vtbuf     = dob;                        // 4M sh (after g4)

  dim3 blk(256);
  // fused weight/x converts: 512 + 1536 + 1536 + 2048 = 5632 blocks
  cvt_all<<<dim3(5632), blk, 0, stream>>>(w_out_l, wbf_out_l, 512,
                                          w_in_g, wbf_in_g, 1536,
                                          w_in_l, wbf_in_l, 1536,
                                          x, wsB, 2048);

  // 1) QKV1 = x @ w_in_l^T + b_in_l
  gemm_bt_bias<128, 0><<<dim3(TD / 128, MM / 128), blk, 0, stream>>>(wsB, wbf_in_l, b_in_l, wsA, MM, TD, DD);
  // 2) local attention (rows pre-permuted for the reshape trick)
  attn_local<<<dim3(BB * CS * HH / 4), blk, 0, stream>>>(wsA, o1);
  // 3) loc2 = O1 @ w_out_l^T + b_out_l  (MT=64: 512 blocks, 2/CU)
  gemm_bt_bias<64, 0><<<dim3(DD / 128, MM / 64), blk, 0, stream>>>(o1, wbf_out_l, b_out_l, wsB, MM, DD, DD);
  // 4) QKV2 = loc2 @ w_in_g^T + b_in_g
  gemm_bt_bias<128, 0><<<dim3(TD / 128, MM / 128), blk, 0, stream>>>(wsB, wbf_in_g, b_in_g, wsA, MM, TD, DD);
  // 5a) V pre-transpose
  transpose_v<<<dim3(BB * HH, SS / 64), blk, 0, stream>>>(wsA, vtbuf);
  // 5b) global attention (in-block K-split, 4 waves: 2 qhalf x 2 khalf)
  attn_global<<<dim3(BB * HH, SS / 64), blk, 0, stream>>>(wsA, wsA + DD, vtbuf, wsB);
  // 5c) convert w_out_g into dead QKV2 space
  cvt_bf16<<<dim3(DD * DD / 2048), blk, 0, stream>>>(w_out_g, wsA, DD * DD);
  // 6) out = O2 @ w_out_g^T + b_out_g  (f32 out, MT=64)
  gemm_bt_bias<64, 1><<<dim3(DD / 128, MM / 64), blk, 0, stream>>>(wsB, wsA, b_out_g, d_out, MM, DD, DD);
}